// Round 4
// baseline (160.756 us; speedup 1.0000x reference)
//
#include <hip/hip_runtime.h>
#include <hip/hip_bf16.h>

typedef __attribute__((ext_vector_type(8))) short short8;
typedef __attribute__((ext_vector_type(4))) float f32x4;
typedef __attribute__((ext_vector_type(16))) float f32x16;
typedef __attribute__((ext_vector_type(4))) unsigned int u32x4;
typedef unsigned short u16;

__device__ __forceinline__ u16 f2bf(float f) {
  __hip_bfloat16 h = __float2bfloat16(f);
  return __builtin_bit_cast(unsigned short, h);
}

__device__ __forceinline__ unsigned pack2(float lo, float hi) {
  return (unsigned)f2bf(lo) | ((unsigned)f2bf(hi) << 16);
}

__device__ __forceinline__ void gload16(const u16* g, u16* l) {
  __builtin_amdgcn_global_load_lds(
      (const __attribute__((address_space(1))) unsigned int*)g,
      (__attribute__((address_space(3))) unsigned int*)l, 16, 0, 0);
}

// ---------- x fp32 -> bf16 ----------
__global__ void cvt_x_kernel(const float* __restrict__ in, u16* __restrict__ out, int n) {
  int i = (blockIdx.x * blockDim.x + threadIdx.x) * 4;
  if (i >= n) return;
  float4 f = *(const float4*)(in + i);
  uint2 pk;
  pk.x = pack2(f.x, f.y);
  pk.y = pack2(f.z, f.w);
  *(uint2*)(out + i) = pk;
}

// ---------- W [1024][N] fp32 -> Wt [N][1024] bf16 ----------
__global__ void tcvt_kernel(const float* __restrict__ in, u16* __restrict__ out, int N) {
  __shared__ float tile[32][33];
  int n0 = blockIdx.x * 32, k0 = blockIdx.y * 32;
  int tx = threadIdx.x, ty = threadIdx.y;  // 32 x 8
#pragma unroll
  for (int r = 0; r < 4; ++r) {
    int k = ty + r * 8;
    tile[k][tx] = in[(size_t)(k0 + k) * N + n0 + tx];
  }
  __syncthreads();
#pragma unroll
  for (int r = 0; r < 4; ++r) {
    int n = ty + r * 8;
    out[(size_t)(n0 + n) * 1024 + k0 + tx] = f2bf(tile[tx][n]);
  }
}

// ---------- GEMM: C[128x128 tile] = A[M][1024] * Bt[N][1024]^T + bias ----------
template <int EPI>
__global__ __launch_bounds__(256, 2) void gemm_kernel(const u16* __restrict__ A,
                                                      const u16* __restrict__ Bt,
                                                      const float* __restrict__ bias,
                                                      void* __restrict__ outp) {
  __shared__ u16 Al[128 * 64];
  __shared__ u16 Bl[128 * 64];
  const int tid = threadIdx.x;
  const int lane = tid & 63, wid = tid >> 6;
  const int l15 = lane & 15, lg = lane >> 4;
  const int wm = wid >> 1, wn = wid & 1;
  const int m0 = blockIdx.y * 128, n0 = blockIdx.x * 128;

  f32x4 acc[4][4] = {};

  for (int k0 = 0; k0 < 1024; k0 += 64) {
    __syncthreads();
#pragma unroll
    for (int i = 0; i < 4; ++i) {
      int p = i * 4096 + tid * 16;
      int row = p >> 7;
      int lslot = ((p >> 4) & 7) ^ (row & 7);
      gload16(A + (size_t)(m0 + row) * 1024 + k0 + lslot * 8, Al + i * 2048 + wid * 512);
      gload16(Bt + (size_t)(n0 + row) * 1024 + k0 + lslot * 8, Bl + i * 2048 + wid * 512);
    }
    __syncthreads();
#pragma unroll
    for (int ks = 0; ks < 2; ++ks) {
      short8 af[4], bfr[4];
#pragma unroll
      for (int m = 0; m < 4; ++m) {
        int row = wm * 64 + m * 16 + l15;
        af[m] = *(const short8*)((const char*)Al + row * 128 + (((ks * 4 + lg) ^ (row & 7)) << 4));
      }
#pragma unroll
      for (int n = 0; n < 4; ++n) {
        int row = wn * 64 + n * 16 + l15;
        bfr[n] = *(const short8*)((const char*)Bl + row * 128 + (((ks * 4 + lg) ^ (row & 7)) << 4));
      }
#pragma unroll
      for (int m = 0; m < 4; ++m)
#pragma unroll
        for (int n = 0; n < 4; ++n)
          acc[m][n] = __builtin_amdgcn_mfma_f32_16x16x32_bf16(af[m], bfr[n], acc[m][n], 0, 0, 0);
    }
  }

  if (EPI == 0) {
    u16* qkv = (u16*)outp;
#pragma unroll
    for (int m = 0; m < 4; ++m)
#pragma unroll
      for (int n = 0; n < 4; ++n) {
        const int gcol = n0 + wn * 64 + n * 16 + l15;
        const int which = gcol >> 10, dd = gcol & 1023;
        const int h = dd >> 6, hd = dd & 63;
        const float bb = bias[gcol];
#pragma unroll
        for (int j = 0; j < 4; ++j) {
          const int grow = m0 + wm * 64 + m * 16 + lg * 4 + j;
          const int b = grow >> 11, s = grow & 2047;
          float v = acc[m][n][j] + bb;
          if (which == 0) v *= 0.18033688011112042f;  // 1/sqrt(64) * log2(e)
          qkv[(size_t)which * 4194304 + ((size_t)(b * 16 + h) * 2048 + s) * 64 + hd] = f2bf(v);
        }
      }
  } else {
    float* O = (float*)outp;
#pragma unroll
    for (int m = 0; m < 4; ++m)
#pragma unroll
      for (int n = 0; n < 4; ++n) {
        const int gcol = n0 + wn * 64 + n * 16 + l15;
        const float bb = bias[gcol];
#pragma unroll
        for (int j = 0; j < 4; ++j) {
          const int grow = m0 + wm * 64 + m * 16 + lg * 4 + j;
          O[(size_t)grow * 1024 + gcol] = acc[m][n][j] + bb;
        }
      }
  }
}

// ---------- causal flash attention, 32x32 MFMA, swapped QK^T, in-register P ----------
// Grid (32, 32): block (x,y) -> q-tile p = 31-x (heavy first), head-batch y.
// Block = 128 threads (2 waves); wave w owns q rows p*64 + w*32 .. +31.
// S^T = mfma(K,Q): lane holds q = q0+(lane&31), 16 kv per subtile in regs.
// Softmax in-lane; P->PV B-operand built via pack + shfl_xor(32) (T12).
// Row-sum via ones-MFMA. K/V double-buffered in LDS, prefetched (T14).
__global__ __launch_bounds__(128, 3) void attn_kernel(const u16* __restrict__ Q,
                                                      const u16* __restrict__ K,
                                                      const u16* __restrict__ V,
                                                      u16* __restrict__ Aout) {
  const int bh = blockIdx.y;        // 0..31
  const int p = 31 - blockIdx.x;    // 0..31, heavy tiles dispatch first
  const int tid = threadIdx.x, lane = tid & 63, wid = tid >> 6;
  const int l31 = lane & 31, h = lane >> 5;

  __shared__ u16 Kl[2][64 * 64];    // [kv][hd], XOR-swizzled 16B slots
  __shared__ u16 Vt[2][64 * 64];    // [hd][kv], XOR-swizzled 16B slots

  const size_t base = (size_t)bh * 2048 * 64;
  const u16* Qb = Q + base;
  const u16* Kb = K + base;
  const u16* Vb = V + base;

  const int q0 = p * 64 + wid * 32;  // wave's first q row
  const int TQ = p;                  // kv tiles 0..p

  // Q as B-operand fragments: lane needs Q[q0+l31][ks*16 + h*8 .. +7]
  short8 qf[4];
#pragma unroll
  for (int ks = 0; ks < 4; ++ks)
    qf[ks] = *(const short8*)(Qb + (size_t)(q0 + l31) * 64 + ks * 16 + h * 8);

  short8 onesf;
#pragma unroll
  for (int j = 0; j < 8; ++j) onesf[j] = (short)0x3F80;

  f32x16 acc_o[2] = {};   // O^T: n-tile hd halves; col=lane&31=q
  f32x16 acc_l = {};      // row-sum (all rows identical; use [0])
  float m = -1e30f;

  // staging geometry (128 threads)
  const int krow = tid >> 3;                     // 0..15 (+16*i)
  const int kslot = tid & 7;                     // dest slot
  const int vhd = tid & 63, vc2 = tid >> 6;      // V gather: hd, chunk parity

  // prologue: stage tile 0
#pragma unroll
  for (int i = 0; i < 4; ++i) {
    const int row = i * 16 + krow;
    gload16(Kb + (size_t)row * 64 + (kslot ^ (row & 7)) * 8, &Kl[0][0] + i * 1024 + wid * 512);
  }
#pragma unroll
  for (int ii = 0; ii < 4; ++ii) {
    const int c = vc2 + 2 * ii;
    short8 vv;
#pragma unroll
    for (int j = 0; j < 8; ++j) vv[j] = (short)Vb[(size_t)(c * 8 + j) * 64 + vhd];
    *(short8*)((char*)&Vt[0][0] + vhd * 128 + ((c ^ (vhd & 7)) << 4)) = vv;
  }
  __syncthreads();

  for (int t = 0; t <= TQ; ++t) {
    const int cur = t & 1;
    const bool pfn = (t < TQ);
    short8 vpf[4];
    if (pfn) {  // issue next tile's staging early; latency hides under compute
      const size_t nb = (size_t)(t + 1) * 64 * 64;
#pragma unroll
      for (int i = 0; i < 4; ++i) {
        const int row = i * 16 + krow;
        gload16(Kb + nb + (size_t)row * 64 + (kslot ^ (row & 7)) * 8,
                &Kl[cur ^ 1][0] + i * 1024 + wid * 512);
      }
#pragma unroll
      for (int ii = 0; ii < 4; ++ii) {
        const int c = vc2 + 2 * ii;
#pragma unroll
        for (int j = 0; j < 8; ++j) vpf[ii][j] = (short)Vb[nb + (size_t)(c * 8 + j) * 64 + vhd];
      }
    }

#pragma unroll
    for (int sub = 0; sub < 2; ++sub) {
      const int kvbase = t * 64 + sub * 32;
      if (kvbase > q0 + 31) break;            // wave-uniform skip (tail subtile)
      const bool diag = (kvbase == q0);

      // K fragments (A-operand): row kv = sub*32 + l31, hd chunk ks*16 + h*8
      short8 kf[4];
#pragma unroll
      for (int ks = 0; ks < 4; ++ks) {
        const int row = sub * 32 + l31;
        kf[ks] = *(const short8*)((const char*)&Kl[cur][0] + row * 128 +
                                  (((ks * 2 + h) ^ (row & 7)) << 4));
      }
      f32x16 sa = {};
#pragma unroll
      for (int ks = 0; ks < 4; ++ks)
        sa = __builtin_amdgcn_mfma_f32_32x32x16_bf16(kf[ks], qf[ks], sa, 0, 0, 0);

      if (diag) {
#pragma unroll
        for (int r = 0; r < 16; ++r) {
          const int kvr = (r & 3) + 8 * (r >> 2) + 4 * h;
          if (kvr > l31) sa[r] = -1e30f;
        }
      }
      // in-lane row max over 16 regs + cross-half
      float rm = fmaxf(fmaxf(fmaxf(sa[0], sa[1]), fmaxf(sa[2], sa[3])),
                       fmaxf(fmaxf(sa[4], sa[5]), fmaxf(sa[6], sa[7])));
      rm = fmaxf(rm, fmaxf(fmaxf(fmaxf(sa[8], sa[9]), fmaxf(sa[10], sa[11])),
                           fmaxf(fmaxf(sa[12], sa[13]), fmaxf(sa[14], sa[15]))));
      rm = fmaxf(rm, __shfl_xor(rm, 32));
      // T13 defer-max (log2 units)
      if (!__all(rm <= m + 5.0f)) {
        const float mn = fmaxf(m, rm);
        const float corr = exp2f(m - mn);
        m = mn;
        acc_l[0] *= corr;
#pragma unroll
        for (int n = 0; n < 2; ++n)
#pragma unroll
          for (int r = 0; r < 16; ++r) acc_o[n][r] *= corr;
      }
#pragma unroll
      for (int r = 0; r < 16; ++r) sa[r] = exp2f(sa[r] - m);

      // pack P pairs and build B-operand frags via cross-half exchange (T12)
      unsigned c[8], s[8];
#pragma unroll
      for (int i = 0; i < 8; ++i) c[i] = pack2(sa[2 * i], sa[2 * i + 1]);
#pragma unroll
      for (int i = 0; i < 8; ++i) s[i] = __shfl_xor(c[i], 32);
      u32x4 w0, w1;
      if (h == 0) {
        w0 = (u32x4){c[0], c[1], s[0], s[1]};
        w1 = (u32x4){c[4], c[5], s[4], s[5]};
      } else {
        w0 = (u32x4){s[2], s[3], c[2], c[3]};
        w1 = (u32x4){s[6], s[7], c[6], c[7]};
      }
      const short8 pk0 = __builtin_bit_cast(short8, w0);
      const short8 pk1 = __builtin_bit_cast(short8, w1);

      // V^T fragments + PV + row-sum
      acc_l = __builtin_amdgcn_mfma_f32_32x32x16_bf16(onesf, pk0, acc_l, 0, 0, 0);
      acc_l = __builtin_amdgcn_mfma_f32_32x32x16_bf16(onesf, pk1, acc_l, 0, 0, 0);
#pragma unroll
      for (int n = 0; n < 2; ++n) {
        const int row = n * 32 + l31;
#pragma unroll
        for (int ks = 0; ks < 2; ++ks) {
          const short8 vf = *(const short8*)((const char*)&Vt[cur][0] + row * 128 +
                                             (((sub * 4 + ks * 2 + h) ^ (row & 7)) << 4));
          acc_o[n] = __builtin_amdgcn_mfma_f32_32x32x16_bf16(vf, ks ? pk1 : pk0, acc_o[n], 0, 0, 0);
        }
      }
    }

    if (pfn) {  // late write of prefetched V into the other buffer
#pragma unroll
      for (int ii = 0; ii < 4; ++ii) {
        const int c = vc2 + 2 * ii;
        *(short8*)((char*)&Vt[cur ^ 1][0] + vhd * 128 + ((c ^ (vhd & 7)) << 4)) = vpf[ii];
      }
    }
    __syncthreads();
  }

  // epilogue: O^T -> Aout[b][q][h*64+hd], packed dword stores
  const int b = bh >> 4, hh = bh & 15;
  const float inv = 1.0f / acc_l[0];
  u16* rowp = Aout + (size_t)(b * 2048 + q0 + l31) * 1024 + hh * 64;
#pragma unroll
  for (int n = 0; n < 2; ++n)
#pragma unroll
    for (int r = 0; r < 16; r += 2) {
      const int hd = n * 32 + (r & 3) + 8 * (r >> 2) + 4 * h;
      *(unsigned*)(rowp + hd) = pack2(acc_o[n][r] * inv, acc_o[n][r + 1] * inv);
    }
}

extern "C" void kernel_launch(void* const* d_in, const int* in_sizes, int n_in,
                              void* d_out, int out_size, void* d_ws, size_t ws_size,
                              hipStream_t stream) {
  const float* x = (const float*)d_in[0];
  const float* Wqkv = (const float*)d_in[1];
  const float* bqkv = (const float*)d_in[2];
  const float* Wout = (const float*)d_in[3];
  const float* bout = (const float*)d_in[4];

  char* ws = (char*)d_ws;
  u16* Xb = (u16*)(ws + 0);            // 8,388,608 B  (reused as Attn later)
  u16* WqkvT = (u16*)(ws + 8388608);   // 6,291,456 B
  u16* WoutT = (u16*)(ws + 14680064);  // 2,097,152 B
  u16* QKV = (u16*)(ws + 16777216);    // 25,165,824 B
  u16* Attn = Xb;

  cvt_x_kernel<<<4096, 256, 0, stream>>>(x, Xb, 4194304);
  tcvt_kernel<<<dim3(96, 32), dim3(32, 8), 0, stream>>>(Wqkv, WqkvT, 3072);
  tcvt_kernel<<<dim3(32, 32), dim3(32, 8), 0, stream>>>(Wout, WoutT, 1024);
  gemm_kernel<0><<<dim3(24, 32), 256, 0, stream>>>(Xb, WqkvT, bqkv, QKV);
  attn_kernel<<<dim3(32, 32), 128, 0, stream>>>(QKV, QKV + 4194304, QKV + 8388608, Attn);
  gemm_kernel<1><<<dim3(8, 32), 256, 0, stream>>>(Attn, WoutT, bout, d_out);
}

// Round 5
// 149.604 us; speedup vs baseline: 1.0745x; 1.0745x over previous
//
#include <hip/hip_runtime.h>
#include <hip/hip_bf16.h>

typedef __attribute__((ext_vector_type(8))) short short8;
typedef __attribute__((ext_vector_type(4))) short short4v;
typedef __attribute__((ext_vector_type(4))) float f32x4;
typedef __attribute__((ext_vector_type(16))) float f32x16;
typedef __attribute__((ext_vector_type(4))) unsigned int u32x4;
typedef unsigned short u16;

__device__ __forceinline__ u16 f2bf(float f) {
  __hip_bfloat16 h = __float2bfloat16(f);
  return __builtin_bit_cast(unsigned short, h);
}

__device__ __forceinline__ unsigned pack2(float lo, float hi) {
  return (unsigned)f2bf(lo) | ((unsigned)f2bf(hi) << 16);
}

__device__ __forceinline__ void gload16(const u16* g, u16* l) {
  __builtin_amdgcn_global_load_lds(
      (const __attribute__((address_space(1))) unsigned int*)g,
      (__attribute__((address_space(3))) unsigned int*)l, 16, 0, 0);
}

// ---------- x fp32 -> bf16 ----------
__global__ void cvt_x_kernel(const float* __restrict__ in, u16* __restrict__ out, int n) {
  int i = (blockIdx.x * blockDim.x + threadIdx.x) * 4;
  if (i >= n) return;
  float4 f = *(const float4*)(in + i);
  uint2 pk;
  pk.x = pack2(f.x, f.y);
  pk.y = pack2(f.z, f.w);
  *(uint2*)(out + i) = pk;
}

// ---------- W [1024][N] fp32 -> Wt [N][1024] bf16 ----------
__global__ void tcvt_kernel(const float* __restrict__ in, u16* __restrict__ out, int N) {
  __shared__ float tile[32][33];
  int n0 = blockIdx.x * 32, k0 = blockIdx.y * 32;
  int tx = threadIdx.x, ty = threadIdx.y;  // 32 x 8
#pragma unroll
  for (int r = 0; r < 4; ++r) {
    int k = ty + r * 8;
    tile[k][tx] = in[(size_t)(k0 + k) * N + n0 + tx];
  }
  __syncthreads();
#pragma unroll
  for (int r = 0; r < 4; ++r) {
    int n = ty + r * 8;
    out[(size_t)(n0 + n) * 1024 + k0 + tx] = f2bf(tile[tx][n]);
  }
}

// ---------- GEMM: C[128x128 tile] = A[M][1024] * Bt[N][1024]^T + bias ----------
// EPI 0: Q,K -> bf16 [b,h,s,64] (Q scaled by 0.125*log2e); V -> TRANSPOSED [b,h,hd,s]
// EPI 1: fp32 out [4096][1024] + bias
template <int EPI>
__global__ __launch_bounds__(256, 2) void gemm_kernel(const u16* __restrict__ A,
                                                      const u16* __restrict__ Bt,
                                                      const float* __restrict__ bias,
                                                      void* __restrict__ outp) {
  __shared__ u16 Al[128 * 64];
  __shared__ u16 Bl[128 * 64];
  const int tid = threadIdx.x;
  const int lane = tid & 63, wid = tid >> 6;
  const int l15 = lane & 15, lg = lane >> 4;
  const int wm = wid >> 1, wn = wid & 1;
  const int m0 = blockIdx.y * 128, n0 = blockIdx.x * 128;

  f32x4 acc[4][4] = {};

  for (int k0 = 0; k0 < 1024; k0 += 64) {
    __syncthreads();
#pragma unroll
    for (int i = 0; i < 4; ++i) {
      int p = i * 4096 + tid * 16;
      int row = p >> 7;
      int lslot = ((p >> 4) & 7) ^ (row & 7);
      gload16(A + (size_t)(m0 + row) * 1024 + k0 + lslot * 8, Al + i * 2048 + wid * 512);
      gload16(Bt + (size_t)(n0 + row) * 1024 + k0 + lslot * 8, Bl + i * 2048 + wid * 512);
    }
    __syncthreads();
#pragma unroll
    for (int ks = 0; ks < 2; ++ks) {
      short8 af[4], bfr[4];
#pragma unroll
      for (int m = 0; m < 4; ++m) {
        int row = wm * 64 + m * 16 + l15;
        af[m] = *(const short8*)((const char*)Al + row * 128 + (((ks * 4 + lg) ^ (row & 7)) << 4));
      }
#pragma unroll
      for (int n = 0; n < 4; ++n) {
        int row = wn * 64 + n * 16 + l15;
        bfr[n] = *(const short8*)((const char*)Bl + row * 128 + (((ks * 4 + lg) ^ (row & 7)) << 4));
      }
#pragma unroll
      for (int m = 0; m < 4; ++m)
#pragma unroll
        for (int n = 0; n < 4; ++n)
          acc[m][n] = __builtin_amdgcn_mfma_f32_16x16x32_bf16(af[m], bfr[n], acc[m][n], 0, 0, 0);
    }
  }

  if (EPI == 0) {
    u16* qkv = (u16*)outp;
#pragma unroll
    for (int m = 0; m < 4; ++m)
#pragma unroll
      for (int n = 0; n < 4; ++n) {
        const int gcol = n0 + wn * 64 + n * 16 + l15;
        const int which = gcol >> 10, dd = gcol & 1023;
        const int h = dd >> 6, hd = dd & 63;
        const float bb = bias[gcol];
        const int grow0 = m0 + wm * 64 + m * 16 + lg * 4;
        const int b = grow0 >> 11, s0 = grow0 & 2047;
        if (which == 2) {
          // V: store transposed [b,h,hd,s] — 4 consecutive s -> one 8B store
          short4v pk;
#pragma unroll
          for (int j = 0; j < 4; ++j) pk[j] = (short)f2bf(acc[m][n][j] + bb);
          *(short4v*)(qkv + (size_t)2 * 4194304 + ((size_t)(b * 16 + h) * 64 + hd) * 2048 + s0) = pk;
        } else {
          const float sc = (which == 0) ? 0.18033688011112042f : 1.0f;  // 1/sqrt(64)*log2e on Q
#pragma unroll
          for (int j = 0; j < 4; ++j) {
            float v = (acc[m][n][j] + bb) * sc;
            qkv[(size_t)which * 4194304 + ((size_t)(b * 16 + h) * 2048 + s0 + j) * 64 + hd] = f2bf(v);
          }
        }
      }
  } else {
    float* O = (float*)outp;
#pragma unroll
    for (int m = 0; m < 4; ++m)
#pragma unroll
      for (int n = 0; n < 4; ++n) {
        const int gcol = n0 + wn * 64 + n * 16 + l15;
        const float bb = bias[gcol];
#pragma unroll
        for (int j = 0; j < 4; ++j) {
          const int grow = m0 + wm * 64 + m * 16 + lg * 4 + j;
          O[(size_t)grow * 1024 + gcol] = acc[m][n][j] + bb;
        }
      }
  }
}

// ---------- causal flash attention, 32x32 MFMA, swapped QK^T, in-register P ----------
// Grid (16, 32). Block = 128 threads (2 waves). Block p handles 64-row q-tiles
// p and 31-p (complement pairing: 33 tile-units of compute per block).
// Wave w owns q rows tile*64 + w*32 .. +31 of BOTH tiles.
// S^T = mfma(K,Q): lane holds q = q0+(lane&31), 16 kv per subtile in regs.
// Softmax in-lane; P->PV B-operand via pack + shfl_xor(32) (T12).
// K and V^T both staged via global_load_lds (V pre-transposed by QKV epilogue),
// double-buffered, prefetch issued before compute (T14).
__global__ __launch_bounds__(128, 2) void attn_kernel(const u16* __restrict__ Q,
                                                      const u16* __restrict__ K,
                                                      const u16* __restrict__ VT,
                                                      u16* __restrict__ Aout) {
  const int bh = blockIdx.y;   // 0..31
  const int p = blockIdx.x;    // 0..15 -> pair (p, 31-p)
  const int tid = threadIdx.x, lane = tid & 63, wid = tid >> 6;
  const int l31 = lane & 31, h = lane >> 5;

  __shared__ u16 Kl[2][64 * 64];   // [kv][hd], XOR-swizzled 16B slots
  __shared__ u16 Vl[2][64 * 64];   // [hd][kv], XOR-swizzled 16B slots

  const u16* Qb = Q + (size_t)bh * 2048 * 64;
  const u16* Kb = K + (size_t)bh * 2048 * 64;
  const u16* Vb = VT + (size_t)bh * 64 * 2048;  // V^T: [hd][s]

  const int qA = p * 64 + wid * 32;
  const int qB = (31 - p) * 64 + wid * 32;
  const int R = 32 - p;  // kv tiles for the heavy member

  short8 qfA[4], qfB[4];
#pragma unroll
  for (int ks = 0; ks < 4; ++ks) {
    qfA[ks] = *(const short8*)(Qb + (size_t)(qA + l31) * 64 + ks * 16 + h * 8);
    qfB[ks] = *(const short8*)(Qb + (size_t)(qB + l31) * 64 + ks * 16 + h * 8);
  }

  f32x16 accA[2] = {}, accB[2] = {};
  float mA = -1e30f, mB = -1e30f, lA = 0.f, lB = 0.f;

  const int srow = tid >> 3, sslot = tid & 7;  // staging: 16 rows x 8 slots per pass

  // prologue: stage tile 0 (K rows=kv stride 64; V^T rows=hd stride 2048)
#pragma unroll
  for (int i = 0; i < 4; ++i) {
    const int row = i * 16 + srow;
    const int sc = (sslot ^ (row & 7)) * 8;
    gload16(Kb + (size_t)row * 64 + sc, &Kl[0][i * 1024 + wid * 512]);
    gload16(Vb + (size_t)row * 2048 + sc, &Vl[0][i * 1024 + wid * 512]);
  }
  __syncthreads();

  for (int t = 0; t < R; ++t) {
    const int cur = t & 1;
    if (t + 1 < R) {  // prefetch next kv tile (T14): issue before compute
      const size_t kb = (size_t)(t + 1) * 64;
#pragma unroll
      for (int i = 0; i < 4; ++i) {
        const int row = i * 16 + srow;
        const int sc = (sslot ^ (row & 7)) * 8;
        gload16(Kb + (kb + row) * 64 + sc, &Kl[cur ^ 1][i * 1024 + wid * 512]);
        gload16(Vb + (size_t)row * 2048 + kb + sc, &Vl[cur ^ 1][i * 1024 + wid * 512]);
      }
    }

#pragma unroll
    for (int sub = 0; sub < 2; ++sub) {
      const int kvbase = t * 64 + sub * 32;
      const bool actA = kvbase <= qA + 31;   // actA implies actB (qA < qB)
      const bool actB = kvbase <= qB + 31;
      if (!actB) continue;

      // K fragments (A-operand) and V^T fragments, shared by both strips
      short8 kf[4], vf[2][2];
#pragma unroll
      for (int ks = 0; ks < 4; ++ks) {
        const int row = sub * 32 + l31;
        kf[ks] = *(const short8*)((const char*)&Kl[cur][0] + row * 128 +
                                  (((ks * 2 + h) ^ (row & 7)) << 4));
      }
#pragma unroll
      for (int n = 0; n < 2; ++n)
#pragma unroll
        for (int ks = 0; ks < 2; ++ks) {
          const int row = n * 32 + l31;
          vf[n][ks] = *(const short8*)((const char*)&Vl[cur][0] + row * 128 +
                                       (((sub * 4 + ks * 2 + h) ^ (row & 7)) << 4));
        }

      auto strip = [&](const short8(&qf)[4], f32x16(&acc)[2], float& m, float& l, int q0) {
        f32x16 sa = {};
#pragma unroll
        for (int ks = 0; ks < 4; ++ks)
          sa = __builtin_amdgcn_mfma_f32_32x32x16_bf16(kf[ks], qf[ks], sa, 0, 0, 0);
        if (kvbase == q0) {  // diagonal subtile
#pragma unroll
          for (int r = 0; r < 16; ++r) {
            const int kvr = (r & 3) + 8 * (r >> 2) + 4 * h;
            if (kvr > l31) sa[r] = -1e30f;
          }
        }
        float rm = fmaxf(fmaxf(fmaxf(sa[0], sa[1]), fmaxf(sa[2], sa[3])),
                         fmaxf(fmaxf(sa[4], sa[5]), fmaxf(sa[6], sa[7])));
        rm = fmaxf(rm, fmaxf(fmaxf(fmaxf(sa[8], sa[9]), fmaxf(sa[10], sa[11])),
                             fmaxf(fmaxf(sa[12], sa[13]), fmaxf(sa[14], sa[15]))));
        rm = fmaxf(rm, __shfl_xor(rm, 32));
        if (!__all(rm <= m + 5.0f)) {  // T13 defer-max (log2 units)
          const float mn = fmaxf(m, rm);
          const float corr = exp2f(m - mn);
          m = mn;
          l *= corr;
#pragma unroll
          for (int n = 0; n < 2; ++n)
#pragma unroll
            for (int r = 0; r < 16; ++r) acc[n][r] *= corr;
        }
#pragma unroll
        for (int r = 0; r < 16; ++r) sa[r] = exp2f(sa[r] - m);
        // row-sum (16 in-lane + cross-half partner has same q)
        float rs = (((sa[0] + sa[1]) + (sa[2] + sa[3])) + ((sa[4] + sa[5]) + (sa[6] + sa[7]))) +
                   (((sa[8] + sa[9]) + (sa[10] + sa[11])) + ((sa[12] + sa[13]) + (sa[14] + sa[15])));
        l += rs + __shfl_xor(rs, 32);
        // pack P^T pairs; build B-operand frags via cross-half exchange (T12)
        unsigned c[8], s[8];
#pragma unroll
        for (int i = 0; i < 8; ++i) c[i] = pack2(sa[2 * i], sa[2 * i + 1]);
#pragma unroll
        for (int i = 0; i < 8; ++i) s[i] = __shfl_xor(c[i], 32);
        u32x4 w0, w1;
        if (h == 0) {
          w0 = (u32x4){c[0], c[1], s[0], s[1]};
          w1 = (u32x4){c[4], c[5], s[4], s[5]};
        } else {
          w0 = (u32x4){s[2], s[3], c[2], c[3]};
          w1 = (u32x4){s[6], s[7], c[6], c[7]};
        }
        const short8 pk0 = __builtin_bit_cast(short8, w0);
        const short8 pk1 = __builtin_bit_cast(short8, w1);
#pragma unroll
        for (int n = 0; n < 2; ++n) {
          acc[n] = __builtin_amdgcn_mfma_f32_32x32x16_bf16(vf[n][0], pk0, acc[n], 0, 0, 0);
          acc[n] = __builtin_amdgcn_mfma_f32_32x32x16_bf16(vf[n][1], pk1, acc[n], 0, 0, 0);
        }
      };

      strip(qfB, accB, mB, lB, qB);
      if (actA) strip(qfA, accA, mA, lA, qA);
    }
    __syncthreads();
  }

  // epilogue: O^T -> Aout[b][q][h*64+hd], packed dword stores
  const int b = bh >> 4, hh = bh & 15;
  {
    const float invA = 1.0f / lA, invB = 1.0f / lB;
    u16* rowA = Aout + (size_t)(b * 2048 + qA + l31) * 1024 + hh * 64;
    u16* rowB = Aout + (size_t)(b * 2048 + qB + l31) * 1024 + hh * 64;
#pragma unroll
    for (int n = 0; n < 2; ++n)
#pragma unroll
      for (int r = 0; r < 16; r += 2) {
        const int hd = n * 32 + (r & 3) + 8 * (r >> 2) + 4 * h;
        *(unsigned*)(rowA + hd) = pack2(accA[n][r] * invA, accA[n][r + 1] * invA);
        *(unsigned*)(rowB + hd) = pack2(accB[n][r] * invB, accB[n][r + 1] * invB);
      }
  }
}

extern "C" void kernel_launch(void* const* d_in, const int* in_sizes, int n_in,
                              void* d_out, int out_size, void* d_ws, size_t ws_size,
                              hipStream_t stream) {
  const float* x = (const float*)d_in[0];
  const float* Wqkv = (const float*)d_in[1];
  const float* bqkv = (const float*)d_in[2];
  const float* Wout = (const float*)d_in[3];
  const float* bout = (const float*)d_in[4];

  char* ws = (char*)d_ws;
  u16* Xb = (u16*)(ws + 0);            // 8,388,608 B  (reused as Attn later)
  u16* WqkvT = (u16*)(ws + 8388608);   // 6,291,456 B
  u16* WoutT = (u16*)(ws + 14680064);  // 2,097,152 B
  u16* QKV = (u16*)(ws + 16777216);    // 25,165,824 B (Q, K, V^T)
  u16* Attn = Xb;

  cvt_x_kernel<<<4096, 256, 0, stream>>>(x, Xb, 4194304);
  tcvt_kernel<<<dim3(96, 32), dim3(32, 8), 0, stream>>>(Wqkv, WqkvT, 3072);
  tcvt_kernel<<<dim3(32, 32), dim3(32, 8), 0, stream>>>(Wout, WoutT, 1024);
  gemm_kernel<0><<<dim3(24, 32), 256, 0, stream>>>(Xb, WqkvT, bqkv, QKV);
  attn_kernel<<<dim3(16, 32), 128, 0, stream>>>(QKV, QKV + 4194304, QKV + 8388608, Attn);
  gemm_kernel<1><<<dim3(8, 32), 256, 0, stream>>>(Attn, WoutT, bout, d_out);
}